// Round 1
// baseline (1336.774 us; speedup 1.0000x reference)
//
#include <hip/hip_runtime.h>
#include <cstdint>
#include <cstddef>

#define H 8
#define C 16
#define DHID 128
#define RPB 8          // rows per block in GEMV-style kernels
#define NEG_SLOPE 0.2f
#define GN_EPS 1e-5f

__device__ __forceinline__ void atomAddF(float* p, float v) {
    __hip_atomic_fetch_add(p, v, __ATOMIC_RELAXED, __HIP_MEMORY_SCOPE_AGENT);
}

// ---------------------------------------------------------------------------
// Fold attention vectors into weight matrices: V[k][h] = sum_c W[k][h*16+c]*att[h][c]
// Also computes bsum = bias_writes + bias_cites.
// grid 4 x 128 threads
// ---------------------------------------------------------------------------
__global__ void fold_kernel(const float* __restrict__ Wsw, const float* __restrict__ asw,
                            const float* __restrict__ Wdw, const float* __restrict__ adw,
                            const float* __restrict__ Wsc, const float* __restrict__ asc,
                            const float* __restrict__ Wdc, const float* __restrict__ adc,
                            const float* __restrict__ bias_w, const float* __restrict__ bias_c,
                            float* __restrict__ Vsw, float* __restrict__ Vdw,
                            float* __restrict__ Vsc, float* __restrict__ Vdc,
                            float* __restrict__ bsum) {
    int k = threadIdx.x;      // 0..127
    int which = blockIdx.x;   // 0..3
    const float* W = which == 0 ? Wsw : which == 1 ? Wdw : which == 2 ? Wsc : Wdc;
    const float* A = which == 0 ? asw : which == 1 ? adw : which == 2 ? asc : adc;
    float* V = which == 0 ? Vsw : which == 1 ? Vdw : which == 2 ? Vsc : Vdc;
    for (int h = 0; h < H; ++h) {
        float s = 0.f;
        for (int c = 0; c < C; ++c) s += W[k * DHID + h * C + c] * A[h * C + c];
        V[k * H + h] = s;
    }
    if (which == 0) bsum[k] = bias_w[k] + bias_c[k];
}

// ---------------------------------------------------------------------------
// Paper projection: emb = relu(x@Wlin+b) (kept in LDS), then
//   xs_c = emb @ Wsrc_cites   (stored, needed for cites messages)
//   a_d_w = emb @ Vd_w, a_s_c = emb @ Vs_c, a_d_c = emb @ Vd_c  (8 scores each)
// block 128 threads handles RPB rows.
// ---------------------------------------------------------------------------
__global__ void paper_proj(const float* __restrict__ x,
                           const float* __restrict__ Wlin, const float* __restrict__ blin,
                           const float* __restrict__ Wsrc_c,
                           const float* __restrict__ Vd_w, const float* __restrict__ Vs_c,
                           const float* __restrict__ Vd_c,
                           float* __restrict__ xs_c,
                           float* __restrict__ a_d_w, float* __restrict__ a_s_c,
                           float* __restrict__ a_d_c, int Np) {
    __shared__ float xr[RPB][DHID];
    __shared__ float er[RPB][DHID];
    int t = threadIdx.x;
    long row0 = (long)blockIdx.x * RPB;
    int nr = (int)min((long)RPB, (long)Np - row0);
    for (int r = 0; r < nr; ++r) xr[r][t] = x[(row0 + r) * DHID + t];
    __syncthreads();
    float acc[RPB];
    float bl = blin[t];
#pragma unroll
    for (int r = 0; r < RPB; ++r) acc[r] = bl;
    for (int k = 0; k < DHID; ++k) {
        float w = Wlin[k * DHID + t];
#pragma unroll
        for (int r = 0; r < RPB; ++r) acc[r] += xr[r][k] * w;
    }
    for (int r = 0; r < nr; ++r) er[r][t] = fmaxf(acc[r], 0.f);
    __syncthreads();
#pragma unroll
    for (int r = 0; r < RPB; ++r) acc[r] = 0.f;
    for (int k = 0; k < DHID; ++k) {
        float w = Wsrc_c[k * DHID + t];
#pragma unroll
        for (int r = 0; r < RPB; ++r) acc[r] += er[r][k] * w;
    }
    for (int r = 0; r < nr; ++r) xs_c[(row0 + r) * DHID + t] = acc[r];
    // attention scores: threads 0..63 -> (row r = t>>3, head h = t&7)
    if (t < RPB * H) {
        int r = t >> 3, h = t & 7;
        if (r < nr) {
            float sdw = 0.f, ssc = 0.f, sdc = 0.f;
            for (int k = 0; k < DHID; ++k) {
                float e = er[r][k];
                sdw += e * Vd_w[k * H + h];
                ssc += e * Vs_c[k * H + h];
                sdc += e * Vd_c[k * H + h];
            }
            a_d_w[(row0 + r) * H + h] = sdw;
            a_s_c[(row0 + r) * H + h] = ssc;
            a_d_c[(row0 + r) * H + h] = sdc;
        }
    }
}

// ---------------------------------------------------------------------------
// Author projection: emb = relu(x@Wlin+b), xs_w = emb@Wsrc_writes, a_s_w scores.
// ---------------------------------------------------------------------------
__global__ void author_proj(const float* __restrict__ x,
                            const float* __restrict__ Wlin, const float* __restrict__ blin,
                            const float* __restrict__ Wsrc_w, const float* __restrict__ Vs_w,
                            float* __restrict__ xs_w, float* __restrict__ a_s_w, int Na) {
    __shared__ float xr[RPB][DHID];
    __shared__ float er[RPB][DHID];
    int t = threadIdx.x;
    long row0 = (long)blockIdx.x * RPB;
    int nr = (int)min((long)RPB, (long)Na - row0);
    for (int r = 0; r < nr; ++r) xr[r][t] = x[(row0 + r) * DHID + t];
    __syncthreads();
    float acc[RPB];
    float bl = blin[t];
#pragma unroll
    for (int r = 0; r < RPB; ++r) acc[r] = bl;
    for (int k = 0; k < DHID; ++k) {
        float w = Wlin[k * DHID + t];
#pragma unroll
        for (int r = 0; r < RPB; ++r) acc[r] += xr[r][k] * w;
    }
    for (int r = 0; r < nr; ++r) er[r][t] = fmaxf(acc[r], 0.f);
    __syncthreads();
#pragma unroll
    for (int r = 0; r < RPB; ++r) acc[r] = 0.f;
    for (int k = 0; k < DHID; ++k) {
        float w = Wsrc_w[k * DHID + t];
#pragma unroll
        for (int r = 0; r < RPB; ++r) acc[r] += er[r][k] * w;
    }
    for (int r = 0; r < nr; ++r) xs_w[(row0 + r) * DHID + t] = acc[r];
    if (t < RPB * H) {
        int r = t >> 3, h = t & 7;
        if (r < nr) {
            float s = 0.f;
            for (int k = 0; k < DHID; ++k) s += er[r][k] * Vs_w[k * H + h];
            a_s_w[(row0 + r) * H + h] = s;
        }
    }
}

// ---------------------------------------------------------------------------
// Edge pass A: denom[dst,h] += exp(leaky_relu(a_s[src,h]+a_d[dst,h]))
// (softmax max-shift skipped: |e| <= ~4, exp cannot overflow; alpha invariant)
// ---------------------------------------------------------------------------
__global__ void edge_denom(const int* __restrict__ src, const int* __restrict__ dst,
                           const float* __restrict__ a_s, const float* __restrict__ a_d,
                           float* __restrict__ denom, int E, int nself) {
    int i = blockIdx.x * blockDim.x + threadIdx.x;
    int total = E + nself;
    if (i >= total) return;
    int s, d;
    if (i < E) { s = src[i]; d = dst[i]; } else { s = d = i - E; }
    const float4* as4 = (const float4*)(a_s + (long)s * H);
    const float4* ad4 = (const float4*)(a_d + (long)d * H);
    float4 a0 = as4[0], a1 = as4[1], b0 = ad4[0], b1 = ad4[1];
    float e[H] = {a0.x + b0.x, a0.y + b0.y, a0.z + b0.z, a0.w + b0.w,
                  a1.x + b1.x, a1.y + b1.y, a1.z + b1.z, a1.w + b1.w};
#pragma unroll
    for (int h = 0; h < H; ++h) {
        float v = e[h] > 0.f ? e[h] : NEG_SLOPE * e[h];
        atomAddF(denom + (long)d * H + h, expf(v));
    }
}

// ---------------------------------------------------------------------------
// Edge pass B: gat[dst,:] += xs[src,:] * alpha   (128 threads per edge)
// ---------------------------------------------------------------------------
__global__ void edge_aggregate(const int* __restrict__ src, const int* __restrict__ dst,
                               const float* __restrict__ a_s, const float* __restrict__ a_d,
                               const float* __restrict__ denom, const float* __restrict__ xs,
                               float* __restrict__ gat, int E, int nself) {
    int lane = threadIdx.x & 127;
    int eoff = threadIdx.x >> 7;
    long i = (long)blockIdx.x * 2 + eoff;
    if (i >= (long)E + nself) return;
    int s, d;
    if (i < E) { s = src[i]; d = dst[i]; } else { s = d = (int)(i - E); }
    int h = lane >> 4;
    float as = a_s[(long)s * H + h];
    float ad = a_d[(long)d * H + h];
    float den = denom[(long)d * H + h];
    float e = as + ad;
    e = e > 0.f ? e : NEG_SLOPE * e;
    float alpha = expf(e) / (den + 1e-16f);
    float v = xs[(long)s * DHID + lane] * alpha;
    atomAddF(gat + (long)d * DHID + lane, v);
}

// ---------------------------------------------------------------------------
// GraphNorm reduction: per-column sum and sum-of-squares of (gat + bsum)
// ---------------------------------------------------------------------------
#define GN_ROWS 128
__global__ void gn_reduce(const float* __restrict__ gat, const float* __restrict__ bsum,
                          float* __restrict__ colsum, float* __restrict__ colsumsq, int Np) {
    int t = threadIdx.x;
    long r0 = (long)blockIdx.x * GN_ROWS;
    long r1 = min(r0 + GN_ROWS, (long)Np);
    float b = bsum[t], s1 = 0.f, s2 = 0.f;
    for (long r = r0; r < r1; ++r) {
        float xv = gat[r * DHID + t] + b;
        s1 += xv;
        s2 += xv * xv;
    }
    atomAddF(colsum + t, s1);
    atomAddF(colsumsq + t, s2);
}

// ---------------------------------------------------------------------------
// Final paper: graphnorm + @W2 + b2 -> d_out
// var = E[x^2] - mu^2 * ms * (2 - ms)   (exact expansion of mean((x-ms*mu)^2))
// ---------------------------------------------------------------------------
__global__ void final_paper(const float* __restrict__ gat, const float* __restrict__ bsum,
                            const float* __restrict__ colsum, const float* __restrict__ colsumsq,
                            const float* __restrict__ gnw, const float* __restrict__ gnb,
                            const float* __restrict__ gnm,
                            const float* __restrict__ W2, const float* __restrict__ b2,
                            float* __restrict__ out, int Np) {
    __shared__ float nrm[RPB][DHID];
    int t = threadIdx.x;
    long row0 = (long)blockIdx.x * RPB;
    float invN = 1.f / (float)Np;
    float mu = colsum[t] * invN;
    float ms = gnm[t];
    float ex2 = colsumsq[t] * invN;
    float var = ex2 - mu * mu * ms * (2.f - ms);
    float scale = gnw[t] * rsqrtf(var + GN_EPS);
    float b = bsum[t], gb = gnb[t];
    int nr = (int)min((long)RPB, (long)Np - row0);
    for (int r = 0; r < nr; ++r) {
        float xv = gat[(row0 + r) * DHID + t] + b;
        nrm[r][t] = (xv - ms * mu) * scale + gb;
    }
    __syncthreads();
    float acc[RPB];
    float bb = b2[t];
#pragma unroll
    for (int r = 0; r < RPB; ++r) acc[r] = bb;
    for (int k = 0; k < DHID; ++k) {
        float w = W2[k * DHID + t];
#pragma unroll
        for (int r = 0; r < RPB; ++r) acc[r] += nrm[r][k] * w;
    }
    for (int r = 0; r < nr; ++r) out[(row0 + r) * DHID + t] = acc[r];
}

// ---------------------------------------------------------------------------
// Author output: gnorm(zeros) == gnb, so every row = gnb@W2_author + b2_author
// ---------------------------------------------------------------------------
__global__ void author_row(const float* __restrict__ gnb_a, const float* __restrict__ W2a,
                           const float* __restrict__ b2a, float* __restrict__ row_a) {
    int t = threadIdx.x;
    float acc = b2a[t];
    for (int k = 0; k < DHID; ++k) acc += gnb_a[k] * W2a[k * DHID + t];
    row_a[t] = acc;
}

__global__ void fill_author(const float* __restrict__ row_a, float* __restrict__ out, long n) {
    long i = (long)blockIdx.x * blockDim.x + threadIdx.x;
    if (i < n) out[i] = row_a[i & (DHID - 1)];
}

// ---------------------------------------------------------------------------
extern "C" void kernel_launch(void* const* d_in, const int* in_sizes, int n_in,
                              void* d_out, int out_size, void* d_ws, size_t ws_size,
                              hipStream_t stream) {
    const float* x_p   = (const float*)d_in[0];
    const float* x_a   = (const float*)d_in[1];
    const int*   e_w   = (const int*)d_in[2];
    const int*   e_c   = (const int*)d_in[3];
    const float* Wlp   = (const float*)d_in[4];
    const float* blp   = (const float*)d_in[5];
    const float* Wla   = (const float*)d_in[6];
    const float* bla   = (const float*)d_in[7];
    const float* Wsw   = (const float*)d_in[8];
    const float* Wdw   = (const float*)d_in[9];
    const float* asw   = (const float*)d_in[10];
    const float* adw   = (const float*)d_in[11];
    const float* bw    = (const float*)d_in[12];
    const float* Wsc   = (const float*)d_in[13];
    const float* Wdc   = (const float*)d_in[14];
    const float* asc   = (const float*)d_in[15];
    const float* adc   = (const float*)d_in[16];
    const float* bc    = (const float*)d_in[17];
    const float* gnw_p = (const float*)d_in[18];
    const float* gnb_p = (const float*)d_in[19];
    const float* gnm_p = (const float*)d_in[20];
    // 21,22,23: gnw/gnb/gnm author
    const float* gnb_a = (const float*)d_in[22];
    const float* W2p   = (const float*)d_in[24];
    const float* b2p   = (const float*)d_in[25];
    const float* W2a   = (const float*)d_in[26];
    const float* b2a   = (const float*)d_in[27];

    int Np = in_sizes[0] / DHID;
    int Na = in_sizes[1] / DHID;
    int Ew = in_sizes[2] / 2;
    int Ec = in_sizes[3] / 2;

    float* ws = (float*)d_ws;
    // ---- zeroed region (one contiguous memset) ----
    float* gat      = ws;                              // Np*128
    float* denom_w  = gat + (size_t)Np * DHID;         // Np*8
    float* denom_c  = denom_w + (size_t)Np * H;        // Np*8
    float* colsum   = denom_c + (size_t)Np * H;        // 128
    float* colsumsq = colsum + DHID;                   // 128
    size_t zero_floats = (size_t)Np * DHID + 2 * (size_t)Np * H + 2 * DHID;
    // ---- written-every-call region ----
    float* xs_w  = colsumsq + DHID;                    // Na*128
    float* xs_c  = xs_w + (size_t)Na * DHID;           // Np*128
    float* a_s_w = xs_c + (size_t)Np * DHID;           // Na*8
    float* a_d_w = a_s_w + (size_t)Na * H;             // Np*8
    float* a_s_c = a_d_w + (size_t)Np * H;             // Np*8
    float* a_d_c = a_s_c + (size_t)Np * H;             // Np*8
    float* Vs_w  = a_d_c + (size_t)Np * H;             // 128*8
    float* Vd_w  = Vs_w + DHID * H;
    float* Vs_c  = Vd_w + DHID * H;
    float* Vd_c  = Vs_c + DHID * H;
    float* bsum  = Vd_c + DHID * H;                    // 128
    float* row_a = bsum + DHID;                        // 128

    hipMemsetAsync(gat, 0, zero_floats * sizeof(float), stream);

    fold_kernel<<<4, 128, 0, stream>>>(Wsw, asw, Wdw, adw, Wsc, asc, Wdc, adc,
                                       bw, bc, Vs_w, Vd_w, Vs_c, Vd_c, bsum);

    paper_proj<<<(Np + RPB - 1) / RPB, 128, 0, stream>>>(
        x_p, Wlp, blp, Wsc, Vd_w, Vs_c, Vd_c, xs_c, a_d_w, a_s_c, a_d_c, Np);
    author_proj<<<(Na + RPB - 1) / RPB, 128, 0, stream>>>(
        x_a, Wla, bla, Wsw, Vs_w, xs_w, a_s_w, Na);

    int nself_w = Na < Np ? Na : Np;   // min(src_count, n_dst)
    int nself_c = Np;

    {
        int tot = Ew + nself_w;
        edge_denom<<<(tot + 255) / 256, 256, 0, stream>>>(e_w, e_w + Ew, a_s_w, a_d_w,
                                                          denom_w, Ew, nself_w);
    }
    {
        int tot = Ec + nself_c;
        edge_denom<<<(tot + 255) / 256, 256, 0, stream>>>(e_c, e_c + Ec, a_s_c, a_d_c,
                                                          denom_c, Ec, nself_c);
    }
    {
        long tot = (long)Ew + nself_w;
        edge_aggregate<<<(tot + 1) / 2, 256, 0, stream>>>(e_w, e_w + Ew, a_s_w, a_d_w,
                                                          denom_w, xs_w, gat, Ew, nself_w);
    }
    {
        long tot = (long)Ec + nself_c;
        edge_aggregate<<<(tot + 1) / 2, 256, 0, stream>>>(e_c, e_c + Ec, a_s_c, a_d_c,
                                                          denom_c, xs_c, gat, Ec, nself_c);
    }

    gn_reduce<<<(Np + GN_ROWS - 1) / GN_ROWS, 128, 0, stream>>>(gat, bsum, colsum, colsumsq, Np);

    final_paper<<<(Np + RPB - 1) / RPB, 128, 0, stream>>>(
        gat, bsum, colsum, colsumsq, gnw_p, gnb_p, gnm_p, W2p, b2p, (float*)d_out, Np);

    author_row<<<1, 128, 0, stream>>>(gnb_a, W2a, b2a, row_a);
    {
        long n = (long)Na * DHID;
        fill_author<<<(n + 255) / 256, 256, 0, stream>>>(row_a, (float*)d_out + (size_t)Np * DHID, n);
    }
}

// Round 2
// 761.096 us; speedup vs baseline: 1.7564x; 1.7564x over previous
//
#include <hip/hip_runtime.h>
#include <cstdint>
#include <cstddef>

#define H 8
#define C 16
#define DHID 128
#define RPB 8          // rows per block in GEMV-style kernels
#define NEG_SLOPE 0.2f
#define GN_EPS 1e-5f

#define SCAN_T 256
#define SCAN_I 4       // 1024 elements per scan block

__device__ __forceinline__ void atomAddF(float* p, float v) {
    __hip_atomic_fetch_add(p, v, __ATOMIC_RELAXED, __HIP_MEMORY_SCOPE_AGENT);
}

// ---------------------------------------------------------------------------
// Fold attention vectors into weight matrices: V[k][h] = sum_c W[k][h*16+c]*att[h][c]
// Also computes bsum = bias_writes + bias_cites.
// ---------------------------------------------------------------------------
__global__ void fold_kernel(const float* __restrict__ Wsw, const float* __restrict__ asw,
                            const float* __restrict__ Wdw, const float* __restrict__ adw,
                            const float* __restrict__ Wsc, const float* __restrict__ asc,
                            const float* __restrict__ Wdc, const float* __restrict__ adc,
                            const float* __restrict__ bias_w, const float* __restrict__ bias_c,
                            float* __restrict__ Vsw, float* __restrict__ Vdw,
                            float* __restrict__ Vsc, float* __restrict__ Vdc,
                            float* __restrict__ bsum) {
    int k = threadIdx.x;      // 0..127
    int which = blockIdx.x;   // 0..3
    const float* W = which == 0 ? Wsw : which == 1 ? Wdw : which == 2 ? Wsc : Wdc;
    const float* A = which == 0 ? asw : which == 1 ? adw : which == 2 ? asc : adc;
    float* V = which == 0 ? Vsw : which == 1 ? Vdw : which == 2 ? Vsc : Vdc;
    for (int h = 0; h < H; ++h) {
        float s = 0.f;
        for (int c = 0; c < C; ++c) s += W[k * DHID + h * C + c] * A[h * C + c];
        V[k * H + h] = s;
    }
    if (which == 0) bsum[k] = bias_w[k] + bias_c[k];
}

// ---------------------------------------------------------------------------
// Paper projection (unchanged from round 1)
// ---------------------------------------------------------------------------
__global__ void paper_proj(const float* __restrict__ x,
                           const float* __restrict__ Wlin, const float* __restrict__ blin,
                           const float* __restrict__ Wsrc_c,
                           const float* __restrict__ Vd_w, const float* __restrict__ Vs_c,
                           const float* __restrict__ Vd_c,
                           float* __restrict__ xs_c,
                           float* __restrict__ a_d_w, float* __restrict__ a_s_c,
                           float* __restrict__ a_d_c, int Np) {
    __shared__ float xr[RPB][DHID];
    __shared__ float er[RPB][DHID];
    int t = threadIdx.x;
    long row0 = (long)blockIdx.x * RPB;
    int nr = (int)min((long)RPB, (long)Np - row0);
    for (int r = 0; r < nr; ++r) xr[r][t] = x[(row0 + r) * DHID + t];
    __syncthreads();
    float acc[RPB];
    float bl = blin[t];
#pragma unroll
    for (int r = 0; r < RPB; ++r) acc[r] = bl;
    for (int k = 0; k < DHID; ++k) {
        float w = Wlin[k * DHID + t];
#pragma unroll
        for (int r = 0; r < RPB; ++r) acc[r] += xr[r][k] * w;
    }
    for (int r = 0; r < nr; ++r) er[r][t] = fmaxf(acc[r], 0.f);
    __syncthreads();
#pragma unroll
    for (int r = 0; r < RPB; ++r) acc[r] = 0.f;
    for (int k = 0; k < DHID; ++k) {
        float w = Wsrc_c[k * DHID + t];
#pragma unroll
        for (int r = 0; r < RPB; ++r) acc[r] += er[r][k] * w;
    }
    for (int r = 0; r < nr; ++r) xs_c[(row0 + r) * DHID + t] = acc[r];
    if (t < RPB * H) {
        int r = t >> 3, h = t & 7;
        if (r < nr) {
            float sdw = 0.f, ssc = 0.f, sdc = 0.f;
            for (int k = 0; k < DHID; ++k) {
                float e = er[r][k];
                sdw += e * Vd_w[k * H + h];
                ssc += e * Vs_c[k * H + h];
                sdc += e * Vd_c[k * H + h];
            }
            a_d_w[(row0 + r) * H + h] = sdw;
            a_s_c[(row0 + r) * H + h] = ssc;
            a_d_c[(row0 + r) * H + h] = sdc;
        }
    }
}

// ---------------------------------------------------------------------------
// Author projection (unchanged from round 1)
// ---------------------------------------------------------------------------
__global__ void author_proj(const float* __restrict__ x,
                            const float* __restrict__ Wlin, const float* __restrict__ blin,
                            const float* __restrict__ Wsrc_w, const float* __restrict__ Vs_w,
                            float* __restrict__ xs_w, float* __restrict__ a_s_w, int Na) {
    __shared__ float xr[RPB][DHID];
    __shared__ float er[RPB][DHID];
    int t = threadIdx.x;
    long row0 = (long)blockIdx.x * RPB;
    int nr = (int)min((long)RPB, (long)Na - row0);
    for (int r = 0; r < nr; ++r) xr[r][t] = x[(row0 + r) * DHID + t];
    __syncthreads();
    float acc[RPB];
    float bl = blin[t];
#pragma unroll
    for (int r = 0; r < RPB; ++r) acc[r] = bl;
    for (int k = 0; k < DHID; ++k) {
        float w = Wlin[k * DHID + t];
#pragma unroll
        for (int r = 0; r < RPB; ++r) acc[r] += xr[r][k] * w;
    }
    for (int r = 0; r < nr; ++r) er[r][t] = fmaxf(acc[r], 0.f);
    __syncthreads();
#pragma unroll
    for (int r = 0; r < RPB; ++r) acc[r] = 0.f;
    for (int k = 0; k < DHID; ++k) {
        float w = Wsrc_w[k * DHID + t];
#pragma unroll
        for (int r = 0; r < RPB; ++r) acc[r] += er[r][k] * w;
    }
    for (int r = 0; r < nr; ++r) xs_w[(row0 + r) * DHID + t] = acc[r];
    if (t < RPB * H) {
        int r = t >> 3, h = t & 7;
        if (r < nr) {
            float s = 0.f;
            for (int k = 0; k < DHID; ++k) s += er[r][k] * Vs_w[k * H + h];
            a_s_w[(row0 + r) * H + h] = s;
        }
    }
}

// ---------------------------------------------------------------------------
// CSR build: degree histogram (edges + implicit self-loops)
// ---------------------------------------------------------------------------
__global__ void deg_hist(const int* __restrict__ dst, int E, int nself, int* __restrict__ deg) {
    int i = blockIdx.x * blockDim.x + threadIdx.x;
    if (i < E) atomicAdd(&deg[dst[i]], 1);
    else if (i < E + nself) atomicAdd(&deg[i - E], 1);
}

// Exclusive scan, pass 1: per-block scan + block totals. Safe in-place (out==in).
__global__ void scan1(const int* __restrict__ in, int n, int* __restrict__ out,
                      int* __restrict__ bsums) {
    __shared__ int sh[SCAN_T];
    int t = threadIdx.x;
    long base = (long)blockIdx.x * SCAN_T * SCAN_I;
    int v[SCAN_I];
    int s = 0;
#pragma unroll
    for (int j = 0; j < SCAN_I; ++j) {
        long idx = base + (long)t * SCAN_I + j;
        v[j] = (idx < n) ? in[idx] : 0;
        s += v[j];
    }
    sh[t] = s;
    __syncthreads();
    for (int off = 1; off < SCAN_T; off <<= 1) {
        int x = (t >= off) ? sh[t - off] : 0;
        __syncthreads();
        sh[t] += x;
        __syncthreads();
    }
    int run = sh[t] - s;   // exclusive prefix of this thread's chunk
#pragma unroll
    for (int j = 0; j < SCAN_I; ++j) {
        long idx = base + (long)t * SCAN_I + j;
        if (idx < n) out[idx] = run;
        run += v[j];
    }
    if (t == SCAN_T - 1) bsums[blockIdx.x] = sh[SCAN_T - 1];
}

// pass 3: add block offsets, write sentinel, init cursors
__global__ void scan3(int* __restrict__ off, const int* __restrict__ bsums, int n, int total,
                      int* __restrict__ cur) {
    int i = blockIdx.x * blockDim.x + threadIdx.x;
    if (i < n) {
        int v = off[i] + bsums[i / (SCAN_T * SCAN_I)];
        off[i] = v;
        cur[i] = v;
    }
    if (i == n) off[n] = total;
}

// scatter: fill per-dst src lists using atomic cursors
__global__ void csr_scatter(const int* __restrict__ src, const int* __restrict__ dst,
                            int E, int nself, int* __restrict__ cur, int* __restrict__ srcarr) {
    int i = blockIdx.x * blockDim.x + threadIdx.x;
    if (i >= E + nself) return;
    int s, d;
    if (i < E) { s = src[i]; d = dst[i]; } else { s = d = i - E; }
    int pos = atomicAdd(&cur[d], 1);
    srcarr[pos] = s;
}

// ---------------------------------------------------------------------------
// Gather: one 128-thread block per paper. Both edge types, denom in-register.
// thread t owns output element t; head h = t>>4.
// ---------------------------------------------------------------------------
__global__ void gat_gather(const int* __restrict__ offw, const int* __restrict__ srcw,
                           const int* __restrict__ offc, const int* __restrict__ srcc,
                           const float* __restrict__ a_s_w, const float* __restrict__ a_d_w,
                           const float* __restrict__ a_s_c, const float* __restrict__ a_d_c,
                           const float* __restrict__ xs_w, const float* __restrict__ xs_c,
                           float* __restrict__ gat, int Np) {
    int d = blockIdx.x;
    int t = threadIdx.x;
    int h = t >> 4;
    float acc = 0.f;
    // writes edges (author -> paper)
    {
        int b0 = offw[d], b1 = offw[d + 1];
        if (b1 > b0) {
            float ad = a_d_w[(long)d * H + h];
            float den = 0.f;
            for (int i = b0; i < b1; ++i) {
                int s = srcw[i];
                float e = a_s_w[(long)s * H + h] + ad;
                e = e > 0.f ? e : NEG_SLOPE * e;
                den += expf(e);
            }
            float rden = 1.f / (den + 1e-16f);
            for (int i = b0; i < b1; ++i) {
                int s = srcw[i];
                float e = a_s_w[(long)s * H + h] + ad;
                e = e > 0.f ? e : NEG_SLOPE * e;
                acc += expf(e) * rden * xs_w[(long)s * DHID + t];
            }
        }
    }
    // cites edges (paper -> paper)
    {
        int b0 = offc[d], b1 = offc[d + 1];
        if (b1 > b0) {
            float ad = a_d_c[(long)d * H + h];
            float den = 0.f;
            for (int i = b0; i < b1; ++i) {
                int s = srcc[i];
                float e = a_s_c[(long)s * H + h] + ad;
                e = e > 0.f ? e : NEG_SLOPE * e;
                den += expf(e);
            }
            float rden = 1.f / (den + 1e-16f);
            for (int i = b0; i < b1; ++i) {
                int s = srcc[i];
                float e = a_s_c[(long)s * H + h] + ad;
                e = e > 0.f ? e : NEG_SLOPE * e;
                acc += expf(e) * rden * xs_c[(long)s * DHID + t];
            }
        }
    }
    gat[(long)d * DHID + t] = acc;
}

// ---------------------------------------------------------------------------
// GraphNorm reduction: per-column sum and sum-of-squares of (gat + bsum)
// ---------------------------------------------------------------------------
#define GN_ROWS 128
__global__ void gn_reduce(const float* __restrict__ gat, const float* __restrict__ bsum,
                          float* __restrict__ colsum, float* __restrict__ colsumsq, int Np) {
    int t = threadIdx.x;
    long r0 = (long)blockIdx.x * GN_ROWS;
    long r1 = min(r0 + GN_ROWS, (long)Np);
    float b = bsum[t], s1 = 0.f, s2 = 0.f;
    for (long r = r0; r < r1; ++r) {
        float xv = gat[r * DHID + t] + b;
        s1 += xv;
        s2 += xv * xv;
    }
    atomAddF(colsum + t, s1);
    atomAddF(colsumsq + t, s2);
}

// ---------------------------------------------------------------------------
// Final paper: graphnorm + @W2 + b2 -> d_out
// ---------------------------------------------------------------------------
__global__ void final_paper(const float* __restrict__ gat, const float* __restrict__ bsum,
                            const float* __restrict__ colsum, const float* __restrict__ colsumsq,
                            const float* __restrict__ gnw, const float* __restrict__ gnb,
                            const float* __restrict__ gnm,
                            const float* __restrict__ W2, const float* __restrict__ b2,
                            float* __restrict__ out, int Np) {
    __shared__ float nrm[RPB][DHID];
    int t = threadIdx.x;
    long row0 = (long)blockIdx.x * RPB;
    float invN = 1.f / (float)Np;
    float mu = colsum[t] * invN;
    float ms = gnm[t];
    float ex2 = colsumsq[t] * invN;
    float var = ex2 - mu * mu * ms * (2.f - ms);
    float scale = gnw[t] * rsqrtf(var + GN_EPS);
    float b = bsum[t], gb = gnb[t];
    int nr = (int)min((long)RPB, (long)Np - row0);
    for (int r = 0; r < nr; ++r) {
        float xv = gat[(row0 + r) * DHID + t] + b;
        nrm[r][t] = (xv - ms * mu) * scale + gb;
    }
    __syncthreads();
    float acc[RPB];
    float bb = b2[t];
#pragma unroll
    for (int r = 0; r < RPB; ++r) acc[r] = bb;
    for (int k = 0; k < DHID; ++k) {
        float w = W2[k * DHID + t];
#pragma unroll
        for (int r = 0; r < RPB; ++r) acc[r] += nrm[r][k] * w;
    }
    for (int r = 0; r < nr; ++r) out[(row0 + r) * DHID + t] = acc[r];
}

// ---------------------------------------------------------------------------
// Author output: gnorm(zeros) == gnb, so every row = gnb@W2_author + b2_author
// ---------------------------------------------------------------------------
__global__ void author_row(const float* __restrict__ gnb_a, const float* __restrict__ W2a,
                           const float* __restrict__ b2a, float* __restrict__ row_a) {
    int t = threadIdx.x;
    float acc = b2a[t];
    for (int k = 0; k < DHID; ++k) acc += gnb_a[k] * W2a[k * DHID + t];
    row_a[t] = acc;
}

__global__ void fill_author(const float* __restrict__ row_a, float* __restrict__ out, long n) {
    long i = (long)blockIdx.x * blockDim.x + threadIdx.x;
    if (i < n) out[i] = row_a[i & (DHID - 1)];
}

// ---------------------------------------------------------------------------
extern "C" void kernel_launch(void* const* d_in, const int* in_sizes, int n_in,
                              void* d_out, int out_size, void* d_ws, size_t ws_size,
                              hipStream_t stream) {
    const float* x_p   = (const float*)d_in[0];
    const float* x_a   = (const float*)d_in[1];
    const int*   e_w   = (const int*)d_in[2];
    const int*   e_c   = (const int*)d_in[3];
    const float* Wlp   = (const float*)d_in[4];
    const float* blp   = (const float*)d_in[5];
    const float* Wla   = (const float*)d_in[6];
    const float* bla   = (const float*)d_in[7];
    const float* Wsw   = (const float*)d_in[8];
    const float* Wdw   = (const float*)d_in[9];
    const float* asw   = (const float*)d_in[10];
    const float* adw   = (const float*)d_in[11];
    const float* bw    = (const float*)d_in[12];
    const float* Wsc   = (const float*)d_in[13];
    const float* Wdc   = (const float*)d_in[14];
    const float* asc   = (const float*)d_in[15];
    const float* adc   = (const float*)d_in[16];
    const float* bc    = (const float*)d_in[17];
    const float* gnw_p = (const float*)d_in[18];
    const float* gnb_p = (const float*)d_in[19];
    const float* gnm_p = (const float*)d_in[20];
    const float* gnb_a = (const float*)d_in[22];
    const float* W2p   = (const float*)d_in[24];
    const float* b2p   = (const float*)d_in[25];
    const float* W2a   = (const float*)d_in[26];
    const float* b2a   = (const float*)d_in[27];

    int Np = in_sizes[0] / DHID;
    int Na = in_sizes[1] / DHID;
    int Ew = in_sizes[2] / 2;
    int Ec = in_sizes[3] / 2;
    int nself_w = Na < Np ? Na : Np;
    int nself_c = Np;
    int tot_w = Ew + nself_w;
    int tot_c = Ec + nself_c;

    float* ws = (float*)d_ws;
    float* gat   = ws;                                 // Np*128
    float* xs_w  = gat + (size_t)Np * DHID;            // Na*128
    float* xs_c  = xs_w + (size_t)Na * DHID;           // Np*128
    float* a_s_w = xs_c + (size_t)Np * DHID;           // Na*8
    float* a_d_w = a_s_w + (size_t)Na * H;             // Np*8
    float* a_s_c = a_d_w + (size_t)Np * H;             // Np*8
    float* a_d_c = a_s_c + (size_t)Np * H;             // Np*8
    float* Vs_w  = a_d_c + (size_t)Np * H;             // 128*8 each
    float* Vd_w  = Vs_w + DHID * H;
    float* Vs_c  = Vd_w + DHID * H;
    float* Vd_c  = Vs_c + DHID * H;
    float* bsum  = Vd_c + DHID * H;                    // 128
    float* row_a = bsum + DHID;                        // 128
    // ---- zeroed region (one contiguous memset) ----
    float* colsum   = row_a + DHID;                    // 128
    float* colsumsq = colsum + DHID;                   // 128
    int*   degw     = (int*)(colsumsq + DHID);         // Np
    int*   degc     = degw + Np;                       // Np
    size_t zero_bytes = (2 * DHID) * sizeof(float) + 2 * (size_t)Np * sizeof(int);
    // ---- CSR arrays ----
    int* offw  = degc + Np;                            // Np+1
    int* offc  = offw + Np + 1;                        // Np+1
    int* curw  = offc + Np + 1;                        // Np
    int* curc  = curw + Np;                            // Np
    int* srcw  = curc + Np;                            // tot_w
    int* srcc  = srcw + tot_w;                         // tot_c
    int* bs1   = srcc + tot_c;                         // 512
    int* bs2   = bs1 + 512;                            // 512 (scratch for scan of bsums)

    hipMemsetAsync(colsum, 0, zero_bytes, stream);

    fold_kernel<<<4, 128, 0, stream>>>(Wsw, asw, Wdw, adw, Wsc, asc, Wdc, adc,
                                       bw, bc, Vs_w, Vd_w, Vs_c, Vd_c, bsum);

    paper_proj<<<(Np + RPB - 1) / RPB, 128, 0, stream>>>(
        x_p, Wlp, blp, Wsc, Vd_w, Vs_c, Vd_c, xs_c, a_d_w, a_s_c, a_d_c, Np);
    author_proj<<<(Na + RPB - 1) / RPB, 128, 0, stream>>>(
        x_a, Wla, bla, Wsw, Vs_w, xs_w, a_s_w, Na);

    // ---- CSR build (writes) ----
    deg_hist<<<(tot_w + 255) / 256, 256, 0, stream>>>(e_w + Ew, Ew, nself_w, degw);
    deg_hist<<<(tot_c + 255) / 256, 256, 0, stream>>>(e_c + Ec, Ec, nself_c, degc);
    int nb = (Np + SCAN_T * SCAN_I - 1) / (SCAN_T * SCAN_I);
    scan1<<<nb, SCAN_T, 0, stream>>>(degw, Np, offw, bs1);
    scan1<<<nb, SCAN_T, 0, stream>>>(degc, Np, offc, bs2);
    scan1<<<1, SCAN_T, 0, stream>>>(bs1, nb, bs1, bs1 + 480);   // in-place, dummy total slot
    scan1<<<1, SCAN_T, 0, stream>>>(bs2, nb, bs2, bs2 + 480);
    scan3<<<(Np + 256) / 256, 256, 0, stream>>>(offw, bs1, Np, tot_w, curw);
    scan3<<<(Np + 256) / 256, 256, 0, stream>>>(offc, bs2, Np, tot_c, curc);
    csr_scatter<<<(tot_w + 255) / 256, 256, 0, stream>>>(e_w, e_w + Ew, Ew, nself_w, curw, srcw);
    csr_scatter<<<(tot_c + 255) / 256, 256, 0, stream>>>(e_c, e_c + Ec, Ec, nself_c, curc, srcc);

    // ---- fused gather (both edge types, denom in-register, no atomics) ----
    gat_gather<<<Np, 128, 0, stream>>>(offw, srcw, offc, srcc,
                                       a_s_w, a_d_w, a_s_c, a_d_c,
                                       xs_w, xs_c, gat, Np);

    gn_reduce<<<(Np + GN_ROWS - 1) / GN_ROWS, 128, 0, stream>>>(gat, bsum, colsum, colsumsq, Np);

    final_paper<<<(Np + RPB - 1) / RPB, 128, 0, stream>>>(
        gat, bsum, colsum, colsumsq, gnw_p, gnb_p, gnm_p, W2p, b2p, (float*)d_out, Np);

    author_row<<<1, 128, 0, stream>>>(gnb_a, W2a, b2a, row_a);
    {
        long n = (long)Na * DHID;
        fill_author<<<(n + 255) / 256, 256, 0, stream>>>(row_a, (float*)d_out + (size_t)Np * DHID, n);
    }
}